// Round 4
// baseline (497.974 us; speedup 1.0000x reference)
//
#include <hip/hip_runtime.h>
#include <hip/hip_bf16.h>
#include <math.h>

// Problem constants
#define Ln     35
#define CINn   21
#define CINP   24        // padded CIN (multiple of 8 -> aligned b128 im2col reads)
#define Fn     128
#define Kn     9
#define Hn     64
#define GB     16        // batch rows per block
#define SEQ_ROWS   43    // rows 0..3 left pad, 4..38 data, 39..42 right pad
#define SEQ_STRIDE 1040  // 43*24=1032 -> 1040 (8-short align; word stride 520 = 8 mod 32)
#define TILE_STRIDE 136  // 128 + 8 pad

typedef __attribute__((ext_vector_type(8))) short short8;
typedef __attribute__((ext_vector_type(4))) float f32x4;

static __device__ __forceinline__ unsigned short bf16bits(float f) {
    __hip_bfloat16 h = __float2bfloat16(f);
    return *(unsigned short*)&h;
}

// ---------------- single fused kernel: 16 batch rows / block ----------------
__global__ __launch_bounds__(256, 3) void fused_kernel(
    const float* __restrict__ seq,    const int*   __restrict__ plen_arr,
    const float* __restrict__ conv_w, const float* __restrict__ conv_b,
    const float* __restrict__ n_w1,   const float* __restrict__ n_b1,
    const float* __restrict__ n_w2,   const float* __restrict__ n_b2,
    const float* __restrict__ c_w1,   const float* __restrict__ c_b1,
    const float* __restrict__ c_w2,   const float* __restrict__ c_b2,
    const float* __restrict__ navg_w, const float* __restrict__ navg_b,
    const float* __restrict__ cavg_w, const float* __restrict__ cavg_b,
    const float* __restrict__ out_w,  const float* __restrict__ out_b,
    float* __restrict__ out)
{
    __shared__ __align__(16) unsigned short s_seq[GB * SEQ_STRIDE];      // 33280 B
    __shared__ __align__(16) unsigned short s_tile[2][GB * TILE_STRIDE]; // 8704 B
    __shared__ __align__(16) float s_yp[Ln][4][GB];                      // 8960 B
    // overlays on s_seq (dead after the l-loop):
    float* s_y   = (float*)s_seq;            // [2][GB][36] = 1152 floats
    float* s_avg = (float*)s_seq + 1152;     // [4 waves][2][GB] = 128 floats

    const int t    = threadIdx.x;
    const int wave = t >> 6;
    const int lane = t & 63;
    const int quad = lane >> 4;
    const int col  = lane & 15;
    const int b0   = blockIdx.x * GB;

    // ---- zero-init padded seq (pad rows + pad channels must be 0) ----
    {
        uint4* p = (uint4*)s_seq;                    // 33280/16 = 2080 uint4
        for (int i = t; i < (GB * SEQ_STRIDE) / 8; i += 256)
            p[i] = make_uint4(0u, 0u, 0u, 0u);
    }

    // ---- per-lane loop-invariant weight fragments, gathered in-kernel ----
    // conv A-frag (operand-swapped GEMM): A[m=f=16*tile+col][k=kk], kk'=k*24+c
    // MLP  B-frag: B[k=f][n=ng]
    short8 wb[2][7];
    short8 w1b[2][4];
    float  cbias[2][4], navw[2][4], cavw[2][4], b1v[2], w2v[2];
    const int head = wave >> 1;            // 0 = n-head (waves 0,1), 1 = c (waves 2,3)
    #pragma unroll
    for (int tt = 0; tt < 2; tt++) {
        const int ng = (2 * wave + tt) * 16 + col;   // conv f (A m-index) AND mlp n-index
        #pragma unroll
        for (int s = 0; s < 7; s++) {
            short8 v;
            #pragma unroll
            for (int j = 0; j < 8; j++) {
                int kk = 32 * s + quad * 8 + j;
                int k = kk / CINP, c = kk % CINP;
                float f = (k < Kn && c < CINn) ? conv_w[(k * CINn + c) * Fn + ng] : 0.0f;
                v[j] = (short)bf16bits(f);
            }
            wb[tt][s] = v;
        }
        const int nl = ng & 63;
        #pragma unroll
        for (int s = 0; s < 4; s++) {
            short8 v;
            #pragma unroll
            for (int j = 0; j < 8; j++) {
                int k = 32 * s + quad * 8 + j;
                float f = head ? c_w1[k * Hn + nl] : n_w1[k * Hn + nl];
                v[j] = (short)bf16bits(f);
            }
            w1b[tt][s] = v;
        }
        #pragma unroll
        for (int r = 0; r < 4; r++) {
            int fidx = (2 * wave + tt) * 16 + 4 * quad + r;   // conv D^T row -> f
            cbias[tt][r] = conv_b[fidx];
            navw[tt][r]  = navg_w[fidx];
            cavw[tt][r]  = cavg_w[fidx];
        }
        b1v[tt] = head ? c_b1[nl] : n_b1[nl];
        w2v[tt] = head ? c_w2[nl] : n_w2[nl];
    }
    const int plen_lane = plen_arr[b0 + col];   // this lane's batch (=col) plen

    __syncthreads();   // zero-init done before data fill

    // ---- stage seq -> bf16 LDS, rows shifted +4 (SAME pad), c<21 only ----
    for (int i = t; i < GB * Ln * CINn; i += 256) {
        int bi = i / (Ln * CINn), r = i % (Ln * CINn);
        int l = r / CINn, c = r % CINn;
        s_seq[bi * SEQ_STRIDE + (4 + l) * CINP + c] =
            bf16bits(seq[(size_t)(b0 + bi) * (Ln * CINn) + r]);
    }
    __syncthreads();

    float sum_n[2][4] = {{0.f,0.f,0.f,0.f},{0.f,0.f,0.f,0.f}};
    float sum_c[2][4] = {{0.f,0.f,0.f,0.f},{0.f,0.f,0.f,0.f}};

    for (int l = 0; l < Ln; l++) {
        // ---- conv GEMM (operand-swapped): D^T[f][batch] = W^T * X^T ----
        // B-operand: im2col window, contiguous in padded seq; lane's n = batch = col
        short8 af[7];
        #pragma unroll
        for (int s = 0; s < 7; s++)
            af[s] = *(const short8*)&s_seq[col * SEQ_STRIDE + l * CINP + 32 * s + quad * 8];
        f32x4 cacc[2] = {{0.f,0.f,0.f,0.f},{0.f,0.f,0.f,0.f}};
        #pragma unroll
        for (int s = 0; s < 7; s++) {
            cacc[0] = __builtin_amdgcn_mfma_f32_16x16x32_bf16(wb[0][s], af[s], cacc[0], 0, 0, 0);
            cacc[1] = __builtin_amdgcn_mfma_f32_16x16x32_bf16(wb[1][s], af[s], cacc[1], 0, 0, 0);
        }
        // ---- epilogue: lane holds batch=col, f = 16*(2w+tt)+4q+r ----
        const int buf = l & 1;
        float cm = (l >= 10 + plen_lane && l < 20 + plen_lane) ? 1.0f : 0.0f;
        #pragma unroll
        for (int tt = 0; tt < 2; tt++) {
            float v0 = fmaxf(cacc[tt][0] + cbias[tt][0], 0.0f);
            float v1 = fmaxf(cacc[tt][1] + cbias[tt][1], 0.0f);
            float v2 = fmaxf(cacc[tt][2] + cbias[tt][2], 0.0f);
            float v3 = fmaxf(cacc[tt][3] + cbias[tt][3], 0.0f);
            if (l < 10) {            // wave-uniform: only first 10 iters pay this
                sum_n[tt][0] += v0; sum_n[tt][1] += v1;
                sum_n[tt][2] += v2; sum_n[tt][3] += v3;
            }
            sum_c[tt][0] += cm * v0; sum_c[tt][1] += cm * v1;
            sum_c[tt][2] += cm * v2; sum_c[tt][3] += cm * v3;
            ushort4 pk = { bf16bits(v0), bf16bits(v1), bf16bits(v2), bf16bits(v3) };
            *(ushort4*)&s_tile[buf][col * TILE_STRIDE + (2 * wave + tt) * 16 + 4 * quad] = pk;
        }
        __syncthreads();   // conv tile written -> MLP may read

        // ---- MLP layer1 GEMM: D[m=batch][n=h(2 heads)], K = 128 f ----
        short8 am[4];
        #pragma unroll
        for (int s = 0; s < 4; s++)
            am[s] = *(const short8*)&s_tile[buf][col * TILE_STRIDE + 32 * s + quad * 8];
        f32x4 hacc[2] = {{0.f,0.f,0.f,0.f},{0.f,0.f,0.f,0.f}};
        #pragma unroll
        for (int s = 0; s < 4; s++) {
            hacc[0] = __builtin_amdgcn_mfma_f32_16x16x32_bf16(am[s], w1b[0][s], hacc[0], 0, 0, 0);
            hacc[1] = __builtin_amdgcn_mfma_f32_16x16x32_bf16(am[s], w1b[1][s], hacc[1], 0, 0, 0);
        }
        // ---- y = relu(h+b1) @ w2 : per-lane partial, reduce over 16 cols ----
        float p[4];
        #pragma unroll
        for (int r = 0; r < 4; r++)
            p[r] = fmaxf(hacc[0][r] + b1v[0], 0.f) * w2v[0]
                 + fmaxf(hacc[1][r] + b1v[1], 0.f) * w2v[1];
        #pragma unroll
        for (int r = 0; r < 4; r++) {
            p[r] += __shfl_xor(p[r], 1);
            p[r] += __shfl_xor(p[r], 2);
            p[r] += __shfl_xor(p[r], 4);
            p[r] += __shfl_xor(p[r], 8);
        }
        if (col == 0)
            *(f32x4*)&s_yp[l][wave][quad * 4] = (f32x4){p[0], p[1], p[2], p[3]};
        // WAR on s_tile[buf] (iter l+2) is fenced by iter l+1's barrier.
    }
    // after the last iteration's barrier, s_seq is dead -> s_y/s_avg overlay is safe

    // ---- flank-average partials: lane has batch=col; reduce over quads+waves ----
    {
        float an = 0.f, ac = 0.f;
        #pragma unroll
        for (int tt = 0; tt < 2; tt++)
            #pragma unroll
            for (int r = 0; r < 4; r++) {
                an += sum_n[tt][r] * navw[tt][r];
                ac += sum_c[tt][r] * cavw[tt][r];
            }
        an += __shfl_xor(an, 16); an += __shfl_xor(an, 32);   // sum over quads
        ac += __shfl_xor(ac, 16); ac += __shfl_xor(ac, 32);
        if (quad == 0) {                     // lane < 16: one per batch
            s_avg[wave * 2 * GB + 0 * GB + col] = an;
            s_avg[wave * 2 * GB + 1 * GB + col] = ac;
        }
    }
    __syncthreads();

    // ---- y finalize: y = tanh(partial_w0 + partial_w1 + b2), 1120 values ----
    {
        const float bn = n_b2[0], bc = c_b2[0];
        for (int i = t; i < 2 * GB * Ln; i += 256) {
            int hd = i / (GB * Ln), rem = i % (GB * Ln);
            int m = rem / Ln, l = rem % Ln;
            float v = s_yp[l][hd * 2][m] + s_yp[l][hd * 2 + 1][m] + (hd ? bc : bn);
            s_y[hd * GB * 36 + m * 36 + l] = tanhf(v);
        }
    }
    __syncthreads();

    // ---- final combine: one thread per batch row ----
    if (t < GB) {
        const int m = t;
        const int plen = plen_arr[b0 + m];
        const float* ym = s_y + m * 36;               // n-head row
        const float* yc = s_y + GB * 36 + m * 36;     // c-head row
        float cleaved_n = ym[10];
        float mn = 0.f;   // reference maxes (y+1)*mask over ALL l; unmasked give 0
        for (int l = 11; l < 10 + plen; l++) mn = fmaxf(mn, ym[l] + 1.f);
        float maxpool_n = -(mn - 1.f);
        float cleaved_c = yc[10 + plen - 1];
        float mc = 0.f;
        for (int l = 10; l < 10 + plen - 1; l++) mc = fmaxf(mc, yc[l] + 1.f);
        float maxpool_c = -(mc - 1.f);
        float sn = 0.f, sc = 0.f;
        #pragma unroll
        for (int w = 0; w < 4; w++) {
            sn += s_avg[w * 2 * GB + 0 * GB + m];
            sc += s_avg[w * 2 * GB + 1 * GB + m];
        }
        float avg_n = tanhf(sn * 0.1f + navg_b[0]);
        float avg_c = tanhf(sc * 0.1f + cavg_b[0]);
        float comb = cleaved_n * out_w[0] + maxpool_n * out_w[1] + avg_n * out_w[2]
                   + cleaved_c * out_w[3] + maxpool_c * out_w[4] + avg_c * out_w[5]
                   + out_b[0];
        out[b0 + m] = 1.f / (1.f + expf(-comb));
    }
}

extern "C" void kernel_launch(void* const* d_in, const int* in_sizes, int n_in,
                              void* d_out, int out_size, void* d_ws, size_t ws_size,
                              hipStream_t stream) {
    const int B = in_sizes[1];
    fused_kernel<<<B / GB, 256, 0, stream>>>(
        (const float*)d_in[0],  (const int*)d_in[1],
        (const float*)d_in[2],  (const float*)d_in[3],
        (const float*)d_in[4],  (const float*)d_in[5],
        (const float*)d_in[6],  (const float*)d_in[7],
        (const float*)d_in[8],  (const float*)d_in[9],
        (const float*)d_in[10], (const float*)d_in[11],
        (const float*)d_in[12], (const float*)d_in[13],
        (const float*)d_in[14], (const float*)d_in[15],
        (const float*)d_in[16], (const float*)d_in[17],
        (float*)d_out);
}

// Round 5
// 433.560 us; speedup vs baseline: 1.1486x; 1.1486x over previous
//
#include <hip/hip_runtime.h>
#include <hip/hip_bf16.h>
#include <math.h>

// Problem constants
#define Ln     35
#define CINn   21
#define CINP   24        // padded CIN (multiple of 8 -> aligned b128 im2col reads)
#define Fn     128
#define Kn     9
#define Hn     64
#define GB     16        // batch rows per block
#define SEQ_ROWS   43    // rows 0..3 left pad, 4..38 data, 39..42 right pad
#define SEQ_STRIDE 1032  // 43*24; word-stride 516 = 4 mod 32 -> only free 2-way alias
#define TILE_STRIDE 136  // 128 + 8 pad (word-stride 68 = 4 mod 32)

typedef __attribute__((ext_vector_type(8))) short short8;
typedef __attribute__((ext_vector_type(4))) float f32x4;

static __device__ __forceinline__ unsigned short bf16bits(float f) {
    __hip_bfloat16 h = __float2bfloat16(f);
    return *(unsigned short*)&h;
}

// ---------------- single fused kernel: 16 batch rows / block ----------------
// NOTE: no min-waves arg on launch_bounds — forcing 3 blocks/CU (R4) spilled the
// weight fragments to scratch (VGPR 112->84, 207 MB HBM writes). Natural alloc
// ~112-130 VGPR still admits 3 blocks/CU with 50.7 KB LDS.
__global__ __launch_bounds__(256) void fused_kernel(
    const float* __restrict__ seq,    const int*   __restrict__ plen_arr,
    const float* __restrict__ conv_w, const float* __restrict__ conv_b,
    const float* __restrict__ n_w1,   const float* __restrict__ n_b1,
    const float* __restrict__ n_w2,   const float* __restrict__ n_b2,
    const float* __restrict__ c_w1,   const float* __restrict__ c_b1,
    const float* __restrict__ c_w2,   const float* __restrict__ c_b2,
    const float* __restrict__ navg_w, const float* __restrict__ navg_b,
    const float* __restrict__ cavg_w, const float* __restrict__ cavg_b,
    const float* __restrict__ out_w,  const float* __restrict__ out_b,
    float* __restrict__ out)
{
    __shared__ __align__(16) unsigned short s_seq[GB * SEQ_STRIDE];      // 33024 B
    __shared__ __align__(16) unsigned short s_tile[2][GB * TILE_STRIDE]; // 8704 B
    __shared__ __align__(16) float s_yp[Ln][4][GB];                      // 8960 B
    // overlays on s_seq (dead after the l-loop):
    float* s_y   = (float*)s_seq;            // [2][GB][36] = 1152 floats
    float* s_avg = (float*)s_seq + 1152;     // [4 waves][2][GB] = 128 floats

    const int t    = threadIdx.x;
    const int wave = t >> 6;
    const int lane = t & 63;
    const int quad = lane >> 4;
    const int col  = lane & 15;
    const int b0   = blockIdx.x * GB;

    // ---- zero-init padded seq (pad rows + pad channels must be 0) ----
    {
        uint4* p = (uint4*)s_seq;                    // 33024/16 = 2064 uint4
        for (int i = t; i < (GB * SEQ_STRIDE) / 8; i += 256)
            p[i] = make_uint4(0u, 0u, 0u, 0u);
    }

    // ---- per-lane loop-invariant weight fragments, gathered in-kernel ----
    // conv A-frag (operand-swapped GEMM): A[m=f=16*tile+col][k=kk], kk'=k*24+c
    // MLP  B-frag: B[k=f][n=ng]
    short8 wb[2][7];
    short8 w1b[2][4];
    float  cbias[2][4], b1v[2], w2v[2];
    const int head = wave >> 1;            // 0 = n-head (waves 0,1), 1 = c (waves 2,3)
    #pragma unroll
    for (int tt = 0; tt < 2; tt++) {
        const int ng = (2 * wave + tt) * 16 + col;   // conv f (A m-index) AND mlp n-index
        #pragma unroll
        for (int s = 0; s < 7; s++) {
            short8 v;
            #pragma unroll
            for (int j = 0; j < 8; j++) {
                int kk = 32 * s + quad * 8 + j;
                int k = kk / CINP, c = kk % CINP;
                float f = (k < Kn && c < CINn) ? conv_w[(k * CINn + c) * Fn + ng] : 0.0f;
                v[j] = (short)bf16bits(f);
            }
            wb[tt][s] = v;
        }
        const int nl = ng & 63;
        #pragma unroll
        for (int s = 0; s < 4; s++) {
            short8 v;
            #pragma unroll
            for (int j = 0; j < 8; j++) {
                int k = 32 * s + quad * 8 + j;
                float f = head ? c_w1[k * Hn + nl] : n_w1[k * Hn + nl];
                v[j] = (short)bf16bits(f);
            }
            w1b[tt][s] = v;
        }
        #pragma unroll
        for (int r = 0; r < 4; r++)
            cbias[tt][r] = conv_b[(2 * wave + tt) * 16 + 4 * quad + r];
        b1v[tt] = head ? c_b1[nl] : n_b1[nl];
        w2v[tt] = head ? c_w2[nl] : n_w2[nl];
    }
    const int plen_lane = plen_arr[b0 + col];   // this lane's batch (=col) plen

    __syncthreads();   // zero-init done before data fill

    // ---- stage seq -> bf16 LDS, rows shifted +4 (SAME pad), c<21 only ----
    for (int i = t; i < GB * Ln * CINn; i += 256) {
        int bi = i / (Ln * CINn), r = i % (Ln * CINn);
        int l = r / CINn, c = r % CINn;
        s_seq[bi * SEQ_STRIDE + (4 + l) * CINP + c] =
            bf16bits(seq[(size_t)(b0 + bi) * (Ln * CINn) + r]);
    }
    __syncthreads();

    float sum_n[2][4] = {{0.f,0.f,0.f,0.f},{0.f,0.f,0.f,0.f}};
    float sum_c[2][4] = {{0.f,0.f,0.f,0.f},{0.f,0.f,0.f,0.f}};

    for (int l = 0; l < Ln; l++) {
        // ---- conv GEMM (operand-swapped): D^T[f][batch] = W^T * X^T ----
        short8 af[7];
        #pragma unroll
        for (int s = 0; s < 7; s++)
            af[s] = *(const short8*)&s_seq[col * SEQ_STRIDE + l * CINP + 32 * s + quad * 8];
        f32x4 cacc[2] = {{0.f,0.f,0.f,0.f},{0.f,0.f,0.f,0.f}};
        #pragma unroll
        for (int s = 0; s < 7; s++) {
            cacc[0] = __builtin_amdgcn_mfma_f32_16x16x32_bf16(wb[0][s], af[s], cacc[0], 0, 0, 0);
            cacc[1] = __builtin_amdgcn_mfma_f32_16x16x32_bf16(wb[1][s], af[s], cacc[1], 0, 0, 0);
        }
        // ---- epilogue: lane holds batch=col, f = 16*(2w+tt)+4q+r ----
        const int buf = l & 1;
        float cm = (l >= 10 + plen_lane && l < 20 + plen_lane) ? 1.0f : 0.0f;
        #pragma unroll
        for (int tt = 0; tt < 2; tt++) {
            float v0 = fmaxf(cacc[tt][0] + cbias[tt][0], 0.0f);
            float v1 = fmaxf(cacc[tt][1] + cbias[tt][1], 0.0f);
            float v2 = fmaxf(cacc[tt][2] + cbias[tt][2], 0.0f);
            float v3 = fmaxf(cacc[tt][3] + cbias[tt][3], 0.0f);
            if (l < 10) {            // wave-uniform
                sum_n[tt][0] += v0; sum_n[tt][1] += v1;
                sum_n[tt][2] += v2; sum_n[tt][3] += v3;
            }
            sum_c[tt][0] += cm * v0; sum_c[tt][1] += cm * v1;
            sum_c[tt][2] += cm * v2; sum_c[tt][3] += cm * v3;
            ushort4 pk = { bf16bits(v0), bf16bits(v1), bf16bits(v2), bf16bits(v3) };
            *(ushort4*)&s_tile[buf][col * TILE_STRIDE + (2 * wave + tt) * 16 + 4 * quad] = pk;
        }
        __syncthreads();   // conv tile written -> MLP may read

        // ---- MLP layer1 GEMM: D[m=batch][n=h(2 heads)], K = 128 f ----
        short8 am[4];
        #pragma unroll
        for (int s = 0; s < 4; s++)
            am[s] = *(const short8*)&s_tile[buf][col * TILE_STRIDE + 32 * s + quad * 8];
        f32x4 hacc[2] = {{0.f,0.f,0.f,0.f},{0.f,0.f,0.f,0.f}};
        #pragma unroll
        for (int s = 0; s < 4; s++) {
            hacc[0] = __builtin_amdgcn_mfma_f32_16x16x32_bf16(am[s], w1b[0][s], hacc[0], 0, 0, 0);
            hacc[1] = __builtin_amdgcn_mfma_f32_16x16x32_bf16(am[s], w1b[1][s], hacc[1], 0, 0, 0);
        }
        // ---- y = relu(h+b1) @ w2 : per-lane partial, reduce over 16 cols ----
        float p[4];
        #pragma unroll
        for (int r = 0; r < 4; r++)
            p[r] = fmaxf(hacc[0][r] + b1v[0], 0.f) * w2v[0]
                 + fmaxf(hacc[1][r] + b1v[1], 0.f) * w2v[1];
        #pragma unroll
        for (int r = 0; r < 4; r++) {
            p[r] += __shfl_xor(p[r], 1);
            p[r] += __shfl_xor(p[r], 2);
            p[r] += __shfl_xor(p[r], 4);
            p[r] += __shfl_xor(p[r], 8);
        }
        if (col == 0)
            *(f32x4*)&s_yp[l][wave][quad * 4] = (f32x4){p[0], p[1], p[2], p[3]};
        // WAR on s_tile[buf] (iter l+2) is fenced by iter l+1's barrier.
    }
    // after the last iteration's barrier, s_seq is dead -> s_y/s_avg overlay safe

    // ---- flank-average partials: apply navg_w/cavg_w post-loop (keeps VGPRs low) ----
    {
        float an = 0.f, ac = 0.f;
        #pragma unroll
        for (int tt = 0; tt < 2; tt++)
            #pragma unroll
            for (int r = 0; r < 4; r++) {
                int fidx = (2 * wave + tt) * 16 + 4 * quad + r;
                an += sum_n[tt][r] * navg_w[fidx];
                ac += sum_c[tt][r] * cavg_w[fidx];
            }
        an += __shfl_xor(an, 16); an += __shfl_xor(an, 32);   // sum over quads
        ac += __shfl_xor(ac, 16); ac += __shfl_xor(ac, 32);
        if (quad == 0) {                     // lane < 16: one per batch
            s_avg[wave * 2 * GB + 0 * GB + col] = an;
            s_avg[wave * 2 * GB + 1 * GB + col] = ac;
        }
    }
    __syncthreads();

    // ---- y finalize: y = tanh(partial_w0 + partial_w1 + b2), 1120 values ----
    {
        const float bn = n_b2[0], bc = c_b2[0];
        for (int i = t; i < 2 * GB * Ln; i += 256) {
            int hd = i / (GB * Ln), rem = i % (GB * Ln);
            int m = rem / Ln, l = rem % Ln;
            float v = s_yp[l][hd * 2][m] + s_yp[l][hd * 2 + 1][m] + (hd ? bc : bn);
            s_y[hd * GB * 36 + m * 36 + l] = tanhf(v);
        }
    }
    __syncthreads();

    // ---- final combine: one thread per batch row ----
    if (t < GB) {
        const int m = t;
        const int plen = plen_arr[b0 + m];
        const float* ym = s_y + m * 36;               // n-head row
        const float* yc = s_y + GB * 36 + m * 36;     // c-head row
        float cleaved_n = ym[10];
        float mn = 0.f;   // reference maxes (y+1)*mask over ALL l; unmasked give 0
        for (int l = 11; l < 10 + plen; l++) mn = fmaxf(mn, ym[l] + 1.f);
        float maxpool_n = -(mn - 1.f);
        float cleaved_c = yc[10 + plen - 1];
        float mc = 0.f;
        for (int l = 10; l < 10 + plen - 1; l++) mc = fmaxf(mc, yc[l] + 1.f);
        float maxpool_c = -(mc - 1.f);
        float sn = 0.f, sc = 0.f;
        #pragma unroll
        for (int w = 0; w < 4; w++) {
            sn += s_avg[w * 2 * GB + 0 * GB + m];
            sc += s_avg[w * 2 * GB + 1 * GB + m];
        }
        float avg_n = tanhf(sn * 0.1f + navg_b[0]);
        float avg_c = tanhf(sc * 0.1f + cavg_b[0]);
        float comb = cleaved_n * out_w[0] + maxpool_n * out_w[1] + avg_n * out_w[2]
                   + cleaved_c * out_w[3] + maxpool_c * out_w[4] + avg_c * out_w[5]
                   + out_b[0];
        out[b0 + m] = 1.f / (1.f + expf(-comb));
    }
}

extern "C" void kernel_launch(void* const* d_in, const int* in_sizes, int n_in,
                              void* d_out, int out_size, void* d_ws, size_t ws_size,
                              hipStream_t stream) {
    const int B = in_sizes[1];
    fused_kernel<<<B / GB, 256, 0, stream>>>(
        (const float*)d_in[0],  (const int*)d_in[1],
        (const float*)d_in[2],  (const float*)d_in[3],
        (const float*)d_in[4],  (const float*)d_in[5],
        (const float*)d_in[6],  (const float*)d_in[7],
        (const float*)d_in[8],  (const float*)d_in[9],
        (const float*)d_in[10], (const float*)d_in[11],
        (const float*)d_in[12], (const float*)d_in[13],
        (const float*)d_in[14], (const float*)d_in[15],
        (const float*)d_in[16], (const float*)d_in[17],
        (float*)d_out);
}

// Round 6
// 419.088 us; speedup vs baseline: 1.1882x; 1.0345x over previous
//
#include <hip/hip_runtime.h>
#include <hip/hip_bf16.h>
#include <math.h>

// Problem constants
#define Ln     35
#define CINn   21
#define CINP   24        // padded CIN (multiple of 8 -> aligned b128 im2col reads)
#define Fn     128
#define Kn     9
#define Hn     64
#define GB     16        // batch rows per block
#define SEQ_STRIDE 1064  // 44 rows*24 + 8 slack; l=35 window ends exactly at 1064.
                         // word-stride 532 = 20 mod 32 -> 8-bank spread (gcd 4)
#define TILE_STRIDE 136  // 128 + 8 pad

typedef __attribute__((ext_vector_type(8))) short short8;
typedef __attribute__((ext_vector_type(4))) float f32x4;

static __device__ __forceinline__ unsigned short bf16bits(float f) {
    __hip_bfloat16 h = __float2bfloat16(f);
    return *(unsigned short*)&h;
}

// ---------------- single fused kernel: 16 batch rows / block ----------------
// launch_bounds(256,2): cap 256 VGPR (2 waves/SIMD tier = the 2 blocks/CU we
// actually get). R4 showed forcing 3 blocks/CU spills the VALU working set.
__global__ __launch_bounds__(256, 2) void fused_kernel(
    const float* __restrict__ seq,    const int*   __restrict__ plen_arr,
    const float* __restrict__ conv_w, const float* __restrict__ conv_b,
    const float* __restrict__ n_w1,   const float* __restrict__ n_b1,
    const float* __restrict__ n_w2,   const float* __restrict__ n_b2,
    const float* __restrict__ c_w1,   const float* __restrict__ c_b1,
    const float* __restrict__ c_w2,   const float* __restrict__ c_b2,
    const float* __restrict__ navg_w, const float* __restrict__ navg_b,
    const float* __restrict__ cavg_w, const float* __restrict__ cavg_b,
    const float* __restrict__ out_w,  const float* __restrict__ out_b,
    float* __restrict__ out)
{
    __shared__ __align__(16) unsigned short s_seq[GB * SEQ_STRIDE];      // 34048 B
    __shared__ __align__(16) unsigned short s_tile[4][GB * TILE_STRIDE]; // 17408 B
    __shared__ __align__(16) float s_yp[Ln][4][GB];                      // 8960 B
    // overlays on s_seq (dead after the l-loop):
    float* s_y   = (float*)s_seq;            // [2][GB][36] = 1152 floats
    float* s_avg = (float*)s_seq + 1152;     // [4 waves][2][GB] = 128 floats

    const int t    = threadIdx.x;
    const int wave = t >> 6;
    const int lane = t & 63;
    const int quad = lane >> 4;
    const int col  = lane & 15;
    const int b0   = blockIdx.x * GB;

    // ---- zero-init padded seq (pad rows/channels + slack must be 0) ----
    {
        uint4* p = (uint4*)s_seq;                    // 34048/16 = 2128 uint4
        for (int i = t; i < (GB * SEQ_STRIDE) / 8; i += 256)
            p[i] = make_uint4(0u, 0u, 0u, 0u);
    }

    // ---- per-lane loop-invariant weight fragments, gathered in-kernel ----
    // conv A-frag (operand-swapped GEMM): A[m=f=16*tile+col][k=kk], kk'=k*24+c
    // MLP  B-frag: B[k=f][n=ng]
    short8 wb[2][7];
    short8 w1b[2][4];
    float  cbias[2][4], b1v[2], w2v[2];
    const int head = wave >> 1;            // 0 = n-head (waves 0,1), 1 = c (waves 2,3)
    #pragma unroll
    for (int tt = 0; tt < 2; tt++) {
        const int ng = (2 * wave + tt) * 16 + col;   // conv f (A m-index) AND mlp n-index
        #pragma unroll
        for (int s = 0; s < 7; s++) {
            short8 v;
            #pragma unroll
            for (int j = 0; j < 8; j++) {
                int kk = 32 * s + quad * 8 + j;
                int k = kk / CINP, c = kk % CINP;
                float f = (k < Kn && c < CINn) ? conv_w[(k * CINn + c) * Fn + ng] : 0.0f;
                v[j] = (short)bf16bits(f);
            }
            wb[tt][s] = v;
        }
        const int nl = ng & 63;
        #pragma unroll
        for (int s = 0; s < 4; s++) {
            short8 v;
            #pragma unroll
            for (int j = 0; j < 8; j++) {
                int k = 32 * s + quad * 8 + j;
                float f = head ? c_w1[k * Hn + nl] : n_w1[k * Hn + nl];
                v[j] = (short)bf16bits(f);
            }
            w1b[tt][s] = v;
        }
        #pragma unroll
        for (int r = 0; r < 4; r++)
            cbias[tt][r] = conv_b[(2 * wave + tt) * 16 + 4 * quad + r];
        b1v[tt] = head ? c_b1[nl] : n_b1[nl];
        w2v[tt] = head ? c_w2[nl] : n_w2[nl];
    }
    const int plen_lane = plen_arr[b0 + col];   // this lane's batch (=col) plen

    __syncthreads();   // zero-init done before data fill

    // ---- stage seq -> bf16 LDS, rows shifted +4 (SAME pad), c<21 only ----
    for (int i = t; i < GB * Ln * CINn; i += 256) {
        int bi = i / (Ln * CINn), r = i % (Ln * CINn);
        int l = r / CINn, c = r % CINn;
        s_seq[bi * SEQ_STRIDE + (4 + l) * CINP + c] =
            bf16bits(seq[(size_t)(b0 + bi) * (Ln * CINn) + r]);
    }
    __syncthreads();

    float sum_n[2][4] = {{0.f,0.f,0.f,0.f},{0.f,0.f,0.f,0.f}};
    float sum_c[2][4] = {{0.f,0.f,0.f,0.f},{0.f,0.f,0.f,0.f}};

    // ---- main loop: TWO l-positions per barrier (18 barriers total).
    // Tile ring of 4 slots (l&3): iter writes slots {2lp&3, 2lp+1&3}, disjoint
    // from previous iter's read slots; WAR on a slot is fenced 1 iter later.
    // l=35 is a pad position: conv+mlp computed, sums auto-masked
    // (cm range [10+plen,20+plen) excludes 35 for plen<=15), y-write guarded.
    for (int l0 = 0; l0 < 36; l0 += 2) {
        const int l1 = l0 + 1;
        // ---- conv GEMM (operand-swapped): D^T[f][batch], 4 indep chains ----
        short8 af0[7], af1[7];
        #pragma unroll
        for (int s = 0; s < 7; s++) {
            af0[s] = *(const short8*)&s_seq[col * SEQ_STRIDE + l0 * CINP + 32 * s + quad * 8];
            af1[s] = *(const short8*)&s_seq[col * SEQ_STRIDE + l1 * CINP + 32 * s + quad * 8];
        }
        f32x4 cacc0[2] = {{0.f,0.f,0.f,0.f},{0.f,0.f,0.f,0.f}};
        f32x4 cacc1[2] = {{0.f,0.f,0.f,0.f},{0.f,0.f,0.f,0.f}};
        #pragma unroll
        for (int s = 0; s < 7; s++) {
            cacc0[0] = __builtin_amdgcn_mfma_f32_16x16x32_bf16(wb[0][s], af0[s], cacc0[0], 0, 0, 0);
            cacc0[1] = __builtin_amdgcn_mfma_f32_16x16x32_bf16(wb[1][s], af0[s], cacc0[1], 0, 0, 0);
            cacc1[0] = __builtin_amdgcn_mfma_f32_16x16x32_bf16(wb[0][s], af1[s], cacc1[0], 0, 0, 0);
            cacc1[1] = __builtin_amdgcn_mfma_f32_16x16x32_bf16(wb[1][s], af1[s], cacc1[1], 0, 0, 0);
        }
        // ---- epilogue for both l: lane holds batch=col, f = 16*(2w+tt)+4q+r ----
        {
            float cm0 = (l0 >= 10 + plen_lane && l0 < 20 + plen_lane) ? 1.0f : 0.0f;
            float cm1 = (l1 >= 10 + plen_lane && l1 < 20 + plen_lane) ? 1.0f : 0.0f;
            #pragma unroll
            for (int tt = 0; tt < 2; tt++) {
                float a0 = fmaxf(cacc0[tt][0] + cbias[tt][0], 0.0f);
                float a1 = fmaxf(cacc0[tt][1] + cbias[tt][1], 0.0f);
                float a2 = fmaxf(cacc0[tt][2] + cbias[tt][2], 0.0f);
                float a3 = fmaxf(cacc0[tt][3] + cbias[tt][3], 0.0f);
                float b0v = fmaxf(cacc1[tt][0] + cbias[tt][0], 0.0f);
                float b1x = fmaxf(cacc1[tt][1] + cbias[tt][1], 0.0f);
                float b2x = fmaxf(cacc1[tt][2] + cbias[tt][2], 0.0f);
                float b3x = fmaxf(cacc1[tt][3] + cbias[tt][3], 0.0f);
                if (l0 < 10) {            // wave-uniform
                    sum_n[tt][0] += a0; sum_n[tt][1] += a1;
                    sum_n[tt][2] += a2; sum_n[tt][3] += a3;
                }
                if (l1 < 10) {
                    sum_n[tt][0] += b0v; sum_n[tt][1] += b1x;
                    sum_n[tt][2] += b2x; sum_n[tt][3] += b3x;
                }
                sum_c[tt][0] += cm0 * a0 + cm1 * b0v;
                sum_c[tt][1] += cm0 * a1 + cm1 * b1x;
                sum_c[tt][2] += cm0 * a2 + cm1 * b2x;
                sum_c[tt][3] += cm0 * a3 + cm1 * b3x;
                ushort4 p0 = { bf16bits(a0), bf16bits(a1), bf16bits(a2), bf16bits(a3) };
                ushort4 p1 = { bf16bits(b0v), bf16bits(b1x), bf16bits(b2x), bf16bits(b3x) };
                *(ushort4*)&s_tile[l0 & 3][col * TILE_STRIDE + (2 * wave + tt) * 16 + 4 * quad] = p0;
                *(ushort4*)&s_tile[l1 & 3][col * TILE_STRIDE + (2 * wave + tt) * 16 + 4 * quad] = p1;
            }
        }
        __syncthreads();   // conv tiles written -> MLP may read

        // ---- MLP layer1 GEMM for both l: D[m=batch][n=h(2 heads)], K=128 ----
        short8 am0[4], am1[4];
        #pragma unroll
        for (int s = 0; s < 4; s++) {
            am0[s] = *(const short8*)&s_tile[l0 & 3][col * TILE_STRIDE + 32 * s + quad * 8];
            am1[s] = *(const short8*)&s_tile[l1 & 3][col * TILE_STRIDE + 32 * s + quad * 8];
        }
        f32x4 hacc0[2] = {{0.f,0.f,0.f,0.f},{0.f,0.f,0.f,0.f}};
        f32x4 hacc1[2] = {{0.f,0.f,0.f,0.f},{0.f,0.f,0.f,0.f}};
        #pragma unroll
        for (int s = 0; s < 4; s++) {
            hacc0[0] = __builtin_amdgcn_mfma_f32_16x16x32_bf16(am0[s], w1b[0][s], hacc0[0], 0, 0, 0);
            hacc0[1] = __builtin_amdgcn_mfma_f32_16x16x32_bf16(am0[s], w1b[1][s], hacc0[1], 0, 0, 0);
            hacc1[0] = __builtin_amdgcn_mfma_f32_16x16x32_bf16(am1[s], w1b[0][s], hacc1[0], 0, 0, 0);
            hacc1[1] = __builtin_amdgcn_mfma_f32_16x16x32_bf16(am1[s], w1b[1][s], hacc1[1], 0, 0, 0);
        }
        // ---- y = relu(h+b1) @ w2 : per-lane partial, reduce over 16 cols ----
        float p0[4], p1[4];
        #pragma unroll
        for (int r = 0; r < 4; r++) {
            p0[r] = fmaxf(hacc0[0][r] + b1v[0], 0.f) * w2v[0]
                  + fmaxf(hacc0[1][r] + b1v[1], 0.f) * w2v[1];
            p1[r] = fmaxf(hacc1[0][r] + b1v[0], 0.f) * w2v[0]
                  + fmaxf(hacc1[1][r] + b1v[1], 0.f) * w2v[1];
        }
        #pragma unroll
        for (int r = 0; r < 4; r++) {
            p0[r] += __shfl_xor(p0[r], 1); p1[r] += __shfl_xor(p1[r], 1);
            p0[r] += __shfl_xor(p0[r], 2); p1[r] += __shfl_xor(p1[r], 2);
            p0[r] += __shfl_xor(p0[r], 4); p1[r] += __shfl_xor(p1[r], 4);
            p0[r] += __shfl_xor(p0[r], 8); p1[r] += __shfl_xor(p1[r], 8);
        }
        if (col == 0) {
            *(f32x4*)&s_yp[l0][wave][quad * 4] = (f32x4){p0[0], p0[1], p0[2], p0[3]};
            if (l1 < Ln)
                *(f32x4*)&s_yp[l1][wave][quad * 4] = (f32x4){p1[0], p1[1], p1[2], p1[3]};
        }
        // next iter writes the other slot pair; WAR fenced by next barrier.
    }
    // after the last iteration's barrier + loop exit, s_seq reads are done.
    __syncthreads();   // ensure ALL waves finished s_seq reads before overlay write

    // ---- flank-average partials: apply navg_w/cavg_w post-loop ----
    {
        float an = 0.f, ac = 0.f;
        #pragma unroll
        for (int tt = 0; tt < 2; tt++)
            #pragma unroll
            for (int r = 0; r < 4; r++) {
                int fidx = (2 * wave + tt) * 16 + 4 * quad + r;
                an += sum_n[tt][r] * navg_w[fidx];
                ac += sum_c[tt][r] * cavg_w[fidx];
            }
        an += __shfl_xor(an, 16); an += __shfl_xor(an, 32);   // sum over quads
        ac += __shfl_xor(ac, 16); ac += __shfl_xor(ac, 32);
        if (quad == 0) {                     // lane < 16: one per batch
            s_avg[wave * 2 * GB + 0 * GB + col] = an;
            s_avg[wave * 2 * GB + 1 * GB + col] = ac;
        }
    }
    __syncthreads();

    // ---- y finalize: y = tanh(partial_w0 + partial_w1 + b2), 1120 values ----
    {
        const float bn = n_b2[0], bc = c_b2[0];
        for (int i = t; i < 2 * GB * Ln; i += 256) {
            int hd = i / (GB * Ln), rem = i % (GB * Ln);
            int m = rem / Ln, l = rem % Ln;
            float v = s_yp[l][hd * 2][m] + s_yp[l][hd * 2 + 1][m] + (hd ? bc : bn);
            s_y[hd * GB * 36 + m * 36 + l] = tanhf(v);
        }
    }
    __syncthreads();

    // ---- final combine: one thread per batch row ----
    if (t < GB) {
        const int m = t;
        const int plen = plen_arr[b0 + m];
        const float* ym = s_y + m * 36;               // n-head row
        const float* yc = s_y + GB * 36 + m * 36;     // c-head row
        float cleaved_n = ym[10];
        float mn = 0.f;   // reference maxes (y+1)*mask over ALL l; unmasked give 0
        for (int l = 11; l < 10 + plen; l++) mn = fmaxf(mn, ym[l] + 1.f);
        float maxpool_n = -(mn - 1.f);
        float cleaved_c = yc[10 + plen - 1];
        float mc = 0.f;
        for (int l = 10; l < 10 + plen - 1; l++) mc = fmaxf(mc, yc[l] + 1.f);
        float maxpool_c = -(mc - 1.f);
        float sn = 0.f, sc = 0.f;
        #pragma unroll
        for (int w = 0; w < 4; w++) {
            sn += s_avg[w * 2 * GB + 0 * GB + m];
            sc += s_avg[w * 2 * GB + 1 * GB + m];
        }
        float avg_n = tanhf(sn * 0.1f + navg_b[0]);
        float avg_c = tanhf(sc * 0.1f + cavg_b[0]);
        float comb = cleaved_n * out_w[0] + maxpool_n * out_w[1] + avg_n * out_w[2]
                   + cleaved_c * out_w[3] + maxpool_c * out_w[4] + avg_c * out_w[5]
                   + out_b[0];
        out[b0 + m] = 1.f / (1.f + expf(-comb));
    }
}

extern "C" void kernel_launch(void* const* d_in, const int* in_sizes, int n_in,
                              void* d_out, int out_size, void* d_ws, size_t ws_size,
                              hipStream_t stream) {
    const int B = in_sizes[1];
    fused_kernel<<<B / GB, 256, 0, stream>>>(
        (const float*)d_in[0],  (const int*)d_in[1],
        (const float*)d_in[2],  (const float*)d_in[3],
        (const float*)d_in[4],  (const float*)d_in[5],
        (const float*)d_in[6],  (const float*)d_in[7],
        (const float*)d_in[8],  (const float*)d_in[9],
        (const float*)d_in[10], (const float*)d_in[11],
        (const float*)d_in[12], (const float*)d_in[13],
        (const float*)d_in[14], (const float*)d_in[15],
        (const float*)d_in[16], (const float*)d_in[17],
        (float*)d_out);
}